// Round 3
// baseline (947.660 us; speedup 1.0000x reference)
//
#include <hip/hip_runtime.h>

// Sggnn_23218593202512 — round 3: dtype fix. Reference is float32 end-to-end
// (rounds 1-2 NaN ⇐ reading f32 arrays as bf16: low-half mantissa bits decode
// to bf16 NaN/Inf; sqrt of garbage bn_v poisons scale tables).
// I/O f32; internal GEMM operands bf16 (no fp32 MFMA on CDNA4), accum f32.
//
// Pipeline:
//  prep: fold BN(+bias) -> per-col f32 scale/offset
//  wtrans: W(f32) -> WT(bf16) [N][K] k-contig
//  A) affinity gemm FUSED: tile of hg=lrelu(sbn(dg@sfc_W+b)) dotted with
//     scl_W in-register -> atomicAdd w_acc[65536] (dg on-the-fly, hg never stored)
//  B) wconv: wT[g2][g1] = bf16(w_acc[g1*256+g2] + scl_b)
//  C) per probe-chunk (ws-adaptive):
//     h   = lrelu(rf1(d @ W1))        bufA  (d on-the-fly from f_p,f_g)
//     t   = lrelu(rf2(h @ W2))        bufB
//     u   = t @ ffc_W                 bufC  (reassoc: (w^T t) ffc = w^T (t ffc))
//     uT  = batch-transpose(u)        bufA
//     feat= lrelu(fbn(wT @ uT + b))   bufC
//     out = feat @ cls_W + cls_b      d_out (f32)

typedef __bf16 bf16;
typedef __attribute__((ext_vector_type(8))) __bf16 bf16x8;
typedef __attribute__((ext_vector_type(4))) __bf16 bf16x4;
typedef __attribute__((ext_vector_type(4))) float f32x4;

#define EPSV 1e-5f

__global__ __launch_bounds__(256) void prep_kernel(
    const float* __restrict__ g, const float* __restrict__ b,
    const float* __restrict__ m, const float* __restrict__ v,
    const float* __restrict__ bias, float* __restrict__ scale,
    float* __restrict__ offset, int n)
{
    int i = blockIdx.x * 256 + threadIdx.x;
    if (i >= n) return;
    float s = g[i] / sqrtf(v[i] + EPSV);
    float o = b[i] - m[i] * s;
    if (bias) o += bias[i] * s;
    scale[i] = s;
    offset[i] = o;
}

// out[n*K + k] = bf16(in[k*N + n])
__global__ __launch_bounds__(256) void wtrans_kernel(
    const float* __restrict__ in, bf16* __restrict__ out, int K, int N)
{
    int k = blockIdx.x * 256 + threadIdx.x;
    int n = blockIdx.y;
    out[(size_t)n * K + k] = (bf16)in[(size_t)k * N + n];
}

// wT[g2*256+g1] = bf16(w_acc[g1*256+g2] + scl_b)
__global__ __launch_bounds__(256) void wconv_kernel(
    const float* __restrict__ w_acc, const float* __restrict__ sclb,
    bf16* __restrict__ wT)
{
    int tid = blockIdx.x * 256 + threadIdx.x;   // 0..65535
    int g2 = tid >> 8, g1 = tid & 255;
    wT[tid] = (bf16)(w_acc[g1 * 256 + g2] + sclb[0]);
}

// u[p*256+g][512] -> uT[p][h][g], 64x64 tiles via f32 LDS.
__global__ __launch_bounds__(256) void utrans_kernel(
    const bf16* __restrict__ u, bf16* __restrict__ uT)
{
    __shared__ float tile[64][65];
    int g0 = blockIdx.x * 64, h0 = blockIdx.y * 64, p = blockIdx.z;
    const bf16* up = u + (size_t)p * 256 * 512;
    bf16* op = uT + (size_t)p * 512 * 256;
    for (int c = threadIdx.x; c < 512; c += 256) {
        int r = c >> 3, hc = (c & 7) * 8;
        bf16x8 val = *(const bf16x8*)(up + (size_t)(g0 + r) * 512 + h0 + hc);
#pragma unroll
        for (int j = 0; j < 8; ++j) tile[r][hc + j] = (float)val[j];
    }
    __syncthreads();
    for (int c = threadIdx.x; c < 512; c += 256) {
        int hr = c >> 3, gc = (c & 7) * 8;
        bf16x8 val;
#pragma unroll
        for (int j = 0; j < 8; ++j) val[j] = (bf16)tile[gc + j][hr];
        *(bf16x8*)(op + (size_t)(h0 + hr) * 256 + g0 + gc) = val;
    }
}

// One wave per row of 512: out[row] = dot(A_bf16[row,:], wv_f32) + bias (f32 out)
__global__ __launch_bounds__(256) void rowdot_kernel(
    const bf16* __restrict__ A, const float* __restrict__ wv,
    const float* __restrict__ bias, float* __restrict__ out)
{
    int wave = threadIdx.x >> 6, lane = threadIdx.x & 63;
    int row = blockIdx.x * 4 + wave;
    bf16x8 a = *(const bf16x8*)(A + (size_t)row * 512 + lane * 8);
    f32x4 w0 = *(const f32x4*)(wv + lane * 8);
    f32x4 w1 = *(const f32x4*)(wv + lane * 8 + 4);
    float s = 0.f;
#pragma unroll
    for (int j = 0; j < 4; ++j) s += (float)a[j] * w0[j];
#pragma unroll
    for (int j = 0; j < 4; ++j) s += (float)a[j + 4] * w1[j];
#pragma unroll
    for (int m = 32; m >= 1; m >>= 1) s += __shfl_xor(s, m, 64);
    if (lane == 0) out[row] = s + bias[0];
}

// C[M,N] = epi(A[M,K] @ BT[N,K]^T). 128x128 tile, BK=32, 4 waves 2x2,
// each wave 64x64 via 4x4 of mfma 16x16x32 bf16.
// pair mode (pairX!=0, f32 inputs): A[r][k] = (X[r>>8][k]-Y[r&255][k])^2*ps[k]+po[k]
// fused-w mode (sclW!=0): rowsum += lrelu(bn(val))*sclW[col] -> atomicAdd w_acc[row]
__global__ __launch_bounds__(256) void gemm_kernel(
    const bf16* __restrict__ A,
    const float* __restrict__ pairX, const float* __restrict__ pairY,
    const float* __restrict__ ps, const float* __restrict__ po,
    const bf16* __restrict__ BT,
    bf16* __restrict__ C,
    int K, int N,
    long long batchB, long long batchC,
    const float* __restrict__ scale, const float* __restrict__ offset,
    int lrelu,
    const float* __restrict__ sclW, float* __restrict__ w_acc)
{
    __shared__ bf16 As[128 * 40];   // row stride 40 bf16 = 80 B
    __shared__ bf16 Bs[128 * 40];
    const int tid  = threadIdx.x;
    const int lane = tid & 63;
    const int wave = tid >> 6;
    const int wr = wave >> 1, wc = wave & 1;
    const int row0 = blockIdx.y * 128;
    const int col0 = blockIdx.x * 128;
    const int q = lane >> 4, l16 = lane & 15;
    const int k0 = q * 8;

    const bf16* Bp = BT + (size_t)blockIdx.z * (size_t)batchB;
    bf16* Cp = C + (size_t)blockIdx.z * (size_t)batchC;

    f32x4 acc[4][4];
#pragma unroll
    for (int mi = 0; mi < 4; ++mi)
#pragma unroll
        for (int ni = 0; ni < 4; ++ni)
#pragma unroll
            for (int e = 0; e < 4; ++e) acc[mi][ni][e] = 0.f;

    for (int kk = 0; kk < K; kk += 32) {
        if (pairX) {
#pragma unroll
            for (int t = 0; t < 4; ++t) {
                int c = tid + t * 256;      // 1024 chunks of 4 f32
                int r = c >> 3;             // 0..127
                int kc = (c & 7) * 4;       // 0,4,..,28
                int gr = row0 + r;
                f32x4 xv = *(const f32x4*)(pairX + (size_t)(gr >> 8) * K + kk + kc);
                f32x4 yv = *(const f32x4*)(pairY + (size_t)(gr & 255) * K + kk + kc);
                bf16x4 dv;
#pragma unroll
                for (int j = 0; j < 4; ++j) {
                    float df = xv[j] - yv[j];
                    dv[j] = (bf16)(df * df * ps[kk + kc + j] + po[kk + kc + j]);
                }
                *(bf16x4*)&As[r * 40 + kc] = dv;
            }
        } else {
#pragma unroll
            for (int t = 0; t < 2; ++t) {
                int c = tid + t * 256;      // 512 chunks of 8 bf16
                int r = c >> 2, kc = (c & 3) * 8;
                *(bf16x8*)&As[r * 40 + kc] =
                    *(const bf16x8*)(A + (size_t)(row0 + r) * K + kk + kc);
            }
        }
#pragma unroll
        for (int t = 0; t < 2; ++t) {
            int c = tid + t * 256;
            int r = c >> 2, kc = (c & 3) * 8;
            *(bf16x8*)&Bs[r * 40 + kc] =
                *(const bf16x8*)(Bp + (size_t)(col0 + r) * K + kk + kc);
        }
        __syncthreads();

        bf16x8 af[4], bfr[4];
#pragma unroll
        for (int mi = 0; mi < 4; ++mi)
            af[mi] = *(const bf16x8*)&As[(wr * 64 + mi * 16 + l16) * 40 + k0];
#pragma unroll
        for (int ni = 0; ni < 4; ++ni)
            bfr[ni] = *(const bf16x8*)&Bs[(wc * 64 + ni * 16 + l16) * 40 + k0];
#pragma unroll
        for (int mi = 0; mi < 4; ++mi)
#pragma unroll
            for (int ni = 0; ni < 4; ++ni)
                acc[mi][ni] = __builtin_amdgcn_mfma_f32_16x16x32_bf16(
                    af[mi], bfr[ni], acc[mi][ni], 0, 0, 0);
        __syncthreads();
    }

    // C/D layout (m89-verified): col = lane&15, row = (lane>>4)*4 + reg
    if (sclW) {
#pragma unroll
        for (int mi = 0; mi < 4; ++mi)
#pragma unroll
            for (int i = 0; i < 4; ++i) {
                float rs = 0.f;
#pragma unroll
                for (int ni = 0; ni < 4; ++ni) {
                    int cc = col0 + wc * 64 + ni * 16 + l16;
                    float val = acc[mi][ni][i] * scale[cc] + offset[cc];
                    val = val > 0.f ? val : 0.1f * val;
                    rs += val * sclW[cc];
                }
                rs += __shfl_xor(rs, 1, 64);
                rs += __shfl_xor(rs, 2, 64);
                rs += __shfl_xor(rs, 4, 64);
                rs += __shfl_xor(rs, 8, 64);
                if (l16 == 0) {
                    int r = row0 + wr * 64 + mi * 16 + q * 4 + i;
                    atomicAdd(w_acc + r, rs);
                }
            }
        return;
    }
#pragma unroll
    for (int mi = 0; mi < 4; ++mi)
#pragma unroll
        for (int ni = 0; ni < 4; ++ni)
#pragma unroll
            for (int i = 0; i < 4; ++i) {
                int r = row0 + wr * 64 + mi * 16 + q * 4 + i;
                int cc = col0 + wc * 64 + ni * 16 + l16;
                float val = acc[mi][ni][i];
                if (scale) val = val * scale[cc] + offset[cc];
                if (lrelu) val = val > 0.f ? val : 0.1f * val;
                Cp[(size_t)r * N + cc] = (bf16)val;
            }
}

extern "C" void kernel_launch(void* const* d_in, const int* in_sizes, int n_in,
                              void* d_out, int out_size, void* d_ws, size_t ws_size,
                              hipStream_t stream)
{
    const float* f_p   = (const float*)d_in[0];
    const float* f_g   = (const float*)d_in[1];
    const float* bn_g  = (const float*)d_in[2];
    const float* bn_b  = (const float*)d_in[3];
    const float* bn_m  = (const float*)d_in[4];
    const float* bn_v  = (const float*)d_in[5];
    const float* rf_W1 = (const float*)d_in[6];
    const float* rf_b1 = (const float*)d_in[7];
    const float* rf1_g = (const float*)d_in[8];
    const float* rf1_b = (const float*)d_in[9];
    const float* rf1_m = (const float*)d_in[10];
    const float* rf1_v = (const float*)d_in[11];
    const float* rf_W2 = (const float*)d_in[12];
    const float* rf_b2 = (const float*)d_in[13];
    const float* rf2_g = (const float*)d_in[14];
    const float* rf2_b = (const float*)d_in[15];
    const float* rf2_m = (const float*)d_in[16];
    const float* rf2_v = (const float*)d_in[17];
    const float* sfc_W = (const float*)d_in[18];
    const float* sfc_b = (const float*)d_in[19];
    const float* sbn_g = (const float*)d_in[20];
    const float* sbn_b = (const float*)d_in[21];
    const float* sbn_m = (const float*)d_in[22];
    const float* sbn_v = (const float*)d_in[23];
    const float* scl_W = (const float*)d_in[24];
    const float* scl_b = (const float*)d_in[25];
    const float* ffc_W = (const float*)d_in[26];
    const float* ffc_b = (const float*)d_in[27];
    const float* fbn_g = (const float*)d_in[28];
    const float* fbn_b = (const float*)d_in[29];
    const float* fbn_m = (const float*)d_in[30];
    const float* fbn_v = (const float*)d_in[31];
    const float* cls_W = (const float*)d_in[32];
    const float* cls_b = (const float*)d_in[33];

    const size_t MB = 1ull << 20;
    char* ws = (char*)d_ws;
    // --- static region: first 8 MiB ---
    float* SC    = (float*)(ws);                 // 32 KiB
    float *s0 = SC,        *o0 = SC + 1024;
    float *s1 = SC + 2048, *o1 = SC + 3072;
    float *s2 = SC + 4096, *o2 = SC + 5120;
    float *s3 = SC + 6144, *o3 = SC + 6656;
    float *s4 = SC + 7168, *o4 = SC + 7680;
    float* w_acc = (float*)(ws + 65536);         // 256 KiB
    bf16* wT     = (bf16*)(ws + 327680);         // 128 KiB
    bf16* W1T    = (bf16*)(ws + 1 * MB);         // 2 MiB
    bf16* W2T    = (bf16*)(ws + 3 * MB);         // 2 MiB
    bf16* sfcT   = (bf16*)(ws + 5 * MB);         // 1 MiB
    bf16* ffcT   = (bf16*)(ws + 6 * MB);         // 1 MiB
    // --- chunked region @ 8 MiB ---
    int nc;
    if      (ws_size >= 48 * MB) nc = 4;
    else if (ws_size >= 28 * MB) nc = 8;
    else                         nc = 16;
    const int pc = 128 / nc;
    const int R  = pc * 256;
    const size_t hbytes = (size_t)R * 1024 * 2;
    bf16* bufA = (bf16*)(ws + 8 * MB);
    bf16* bufB = (bf16*)(ws + 8 * MB + hbytes);
    bf16* bufC = (bf16*)(ws + 8 * MB + 2 * hbytes);

    // 1. BN folds
    prep_kernel<<<dim3(4), 256, 0, stream>>>(bn_g, bn_b, bn_m, bn_v, nullptr, s0, o0, 1024);
    prep_kernel<<<dim3(4), 256, 0, stream>>>(rf1_g, rf1_b, rf1_m, rf1_v, rf_b1, s1, o1, 1024);
    prep_kernel<<<dim3(4), 256, 0, stream>>>(rf2_g, rf2_b, rf2_m, rf2_v, rf_b2, s2, o2, 1024);
    prep_kernel<<<dim3(2), 256, 0, stream>>>(sbn_g, sbn_b, sbn_m, sbn_v, sfc_b, s3, o3, 512);
    prep_kernel<<<dim3(2), 256, 0, stream>>>(fbn_g, fbn_b, fbn_m, fbn_v, ffc_b, s4, o4, 512);

    // 2. weight transposes (f32 -> bf16)
    wtrans_kernel<<<dim3(4, 1024), 256, 0, stream>>>(rf_W1, W1T, 1024, 1024);
    wtrans_kernel<<<dim3(4, 1024), 256, 0, stream>>>(rf_W2, W2T, 1024, 1024);
    wtrans_kernel<<<dim3(4, 512), 256, 0, stream>>>(sfc_W, sfcT, 1024, 512);
    wtrans_kernel<<<dim3(4, 512), 256, 0, stream>>>(ffc_W, ffcT, 1024, 512);

    // 3. fused affinity: w_acc[g1*256+g2] = sum_h lrelu(sbn(dg@sfc_W))*scl_W[h]
    hipMemsetAsync(w_acc, 0, 65536 * sizeof(float), stream);
    gemm_kernel<<<dim3(4, 512, 1), 256, 0, stream>>>(
        nullptr, f_g, f_g, s0, o0, sfcT, nullptr, 1024, 512, 0, 0,
        s3, o3, 1, scl_W, w_acc);
    // 4. wT[g2][g1] = w_acc[g1*256+g2] + scl_b
    wconv_kernel<<<dim3(256), 256, 0, stream>>>(w_acc, scl_b, wT);

    // 5-10. probe chunks
    for (int ci = 0; ci < nc; ++ci) {
        const float* fp_c = f_p + (size_t)ci * pc * 1024;
        gemm_kernel<<<dim3(8, R / 128, 1), 256, 0, stream>>>(
            nullptr, fp_c, f_g, s0, o0, W1T, bufA, 1024, 1024, 0, 0,
            s1, o1, 1, nullptr, nullptr);
        gemm_kernel<<<dim3(8, R / 128, 1), 256, 0, stream>>>(
            bufA, nullptr, nullptr, nullptr, nullptr, W2T, bufB, 1024, 1024, 0, 0,
            s2, o2, 1, nullptr, nullptr);
        gemm_kernel<<<dim3(4, R / 128, 1), 256, 0, stream>>>(
            bufB, nullptr, nullptr, nullptr, nullptr, ffcT, bufC, 1024, 512, 0, 0,
            nullptr, nullptr, 0, nullptr, nullptr);
        utrans_kernel<<<dim3(4, 8, pc), 256, 0, stream>>>(bufC, bufA);
        gemm_kernel<<<dim3(4, 2, pc), 256, 0, stream>>>(
            wT, nullptr, nullptr, nullptr, nullptr, bufA, bufC, 256, 512,
            (long long)512 * 256, (long long)256 * 512, s4, o4, 1, nullptr, nullptr);
        rowdot_kernel<<<dim3(R / 4), 256, 0, stream>>>(
            bufC, cls_W, cls_b, (float*)d_out + (size_t)ci * R);
    }
}

// Round 4
// 655.668 us; speedup vs baseline: 1.4453x; 1.4453x over previous
//
#include <hip/hip_runtime.h>

// Sggnn_23218593202512 — round 4: perf. (1) global_load_lds width-16 staging
// (m97 ladder), stride-32 unpadded LDS tiles; (2) affinity GEMM exploits
// w-symmetry (skip below-diagonal blocks, mirror in wconv); (3) classifier
// rowdot fused into feat-GEMM epilogue (atomicAdd f32 accumulator).
//
// Pipeline (f32 I/O, bf16 MFMA operands, f32 accum):
//  prep: fold BN(+bias) -> per-col f32 scale/offset
//  wtrans: W(f32) -> WT(bf16) [N][K] k-contig
//  A) affinity FUSED+SYM: hg tile = lrelu(sbn(dg@sfc_W+b)) dotted with scl_W
//     in-register -> atomicAdd w_acc (grid.y=384 of 512; dg on-the-fly)
//  B) wconv: wT[g2][g1] = bf16(w_acc[canon(g1,g2)] + scl_b)
//  C) per probe-chunk:
//     h   = lrelu(rf1(d @ W1))        bufA  (pair mode from f_p,f_g)
//     t   = lrelu(rf2(h @ W2))        bufB
//     u   = t @ ffc_W                 bufC  (reassoc: (w^T t) ffc = w^T (t ffc))
//     uT  = batch-transpose(u)        bufA
//     feat-gemm FUSED: lrelu(fbn(wT @ uT + b)) . cls_W -> atomicAdd out_acc
//  D) finout: d_out = out_acc + cls_b

typedef __bf16 bf16;
typedef __attribute__((ext_vector_type(8))) __bf16 bf16x8;
typedef __attribute__((ext_vector_type(4))) float f32x4;

#define EPSV 1e-5f

__device__ __forceinline__ void async_load16(const bf16* g, bf16* l) {
    __builtin_amdgcn_global_load_lds(
        (const __attribute__((address_space(1))) void*)g,
        (__attribute__((address_space(3))) void*)l, 16, 0, 0);
}

__global__ __launch_bounds__(256) void prep_kernel(
    const float* __restrict__ g, const float* __restrict__ b,
    const float* __restrict__ m, const float* __restrict__ v,
    const float* __restrict__ bias, float* __restrict__ scale,
    float* __restrict__ offset, int n)
{
    int i = blockIdx.x * 256 + threadIdx.x;
    if (i >= n) return;
    float s = g[i] / sqrtf(v[i] + EPSV);
    float o = b[i] - m[i] * s;
    if (bias) o += bias[i] * s;
    scale[i] = s;
    offset[i] = o;
}

// out[n*K + k] = bf16(in[k*N + n])
__global__ __launch_bounds__(256) void wtrans_kernel(
    const float* __restrict__ in, bf16* __restrict__ out, int K, int N)
{
    int k = blockIdx.x * 256 + threadIdx.x;
    int n = blockIdx.y;
    out[(size_t)n * K + k] = (bf16)in[(size_t)k * N + n];
}

// wT[g2*256+g1] = bf16(w[g1][g2] + scl_b); below-diagonal quadrant mirrored
__global__ __launch_bounds__(256) void wconv_kernel(
    const float* __restrict__ w_acc, const float* __restrict__ sclb,
    bf16* __restrict__ wT)
{
    int tid = blockIdx.x * 256 + threadIdx.x;   // 0..65535
    int g2 = tid >> 8, g1 = tid & 255;
    int idx = (g1 >= 128 && g2 < 128) ? (g2 * 256 + g1) : (g1 * 256 + g2);
    wT[tid] = (bf16)(w_acc[idx] + sclb[0]);
}

// u[p*256+g][512] -> uT[p][h][g], 64x64 tiles via f32 LDS.
__global__ __launch_bounds__(256) void utrans_kernel(
    const bf16* __restrict__ u, bf16* __restrict__ uT)
{
    __shared__ float tile[64][65];
    int g0 = blockIdx.x * 64, h0 = blockIdx.y * 64, p = blockIdx.z;
    const bf16* up = u + (size_t)p * 256 * 512;
    bf16* op = uT + (size_t)p * 512 * 256;
    for (int c = threadIdx.x; c < 512; c += 256) {
        int r = c >> 3, hc = (c & 7) * 8;
        bf16x8 val = *(const bf16x8*)(up + (size_t)(g0 + r) * 512 + h0 + hc);
#pragma unroll
        for (int j = 0; j < 8; ++j) tile[r][hc + j] = (float)val[j];
    }
    __syncthreads();
    for (int c = threadIdx.x; c < 512; c += 256) {
        int hr = c >> 3, gc = (c & 7) * 8;
        bf16x8 val;
#pragma unroll
        for (int j = 0; j < 8; ++j) val[j] = (bf16)tile[gc + j][hr];
        *(bf16x8*)(op + (size_t)(h0 + hr) * 256 + g0 + gc) = val;
    }
}

__global__ __launch_bounds__(256) void finout_kernel(
    const float* __restrict__ acc, const float* __restrict__ clsb,
    float* __restrict__ out)
{
    int i = blockIdx.x * 256 + threadIdx.x;
    out[i] = acc[i] + clsb[0];
}

// C[M,N] = epi(A[M,K] @ BT[N,K]^T). 128x128 tile, BK=32, 4 waves 2x2,
// wave 64x64 via 4x4 mfma 16x16x32 bf16. LDS stride 32 (unpadded, async-DMA).
// pair mode (pairX!=0, f32): A[r][k] = (X[r>>8][k]-Y[r&255][k])^2*ps[k]+po[k]
// symmap: blockIdx.y remap for symmetric-w skip (affinity only)
// fused mode (fuseW!=0): rs += lrelu(bn(val))*fuseW[col];
//   atomicAdd facc[z*faccStride + row] (no C store)
__global__ __launch_bounds__(256) void gemm_kernel(
    const bf16* __restrict__ A,
    const float* __restrict__ pairX, const float* __restrict__ pairY,
    const float* __restrict__ ps, const float* __restrict__ po,
    const bf16* __restrict__ BT,
    bf16* __restrict__ C,
    int K, int N,
    long long batchB, long long batchC,
    const float* __restrict__ scale, const float* __restrict__ offset,
    int lrelu, int symmap,
    const float* __restrict__ fuseW, float* __restrict__ facc,
    long long faccStride)
{
    __shared__ bf16 As[128 * 32];   // 8 KiB, contiguous (async-DMA layout)
    __shared__ bf16 Bs[128 * 32];
    const int tid  = threadIdx.x;
    const int lane = tid & 63;
    const int wave = tid >> 6;
    const int wr = wave >> 1, wc = wave & 1;
    int by = blockIdx.y;
    if (symmap) by = (by < 128) ? (by * 2) : ((by - 128) * 2 + 1);
    const int row0 = by * 128;
    const int col0 = blockIdx.x * 128;
    const int q = lane >> 4, l16 = lane & 15;
    const int k0 = q * 8;
    const int ar  = lane >> 2;        // async: row within 16-row chunk
    const int akc = (lane & 3) * 8;   // async: k offset (bf16 elems)

    const bf16* Bp = BT + (size_t)blockIdx.z * (size_t)batchB;
    bf16* Cp = C + (size_t)blockIdx.z * (size_t)batchC;

    f32x4 acc[4][4];
#pragma unroll
    for (int mi = 0; mi < 4; ++mi)
#pragma unroll
        for (int ni = 0; ni < 4; ++ni)
#pragma unroll
            for (int e = 0; e < 4; ++e) acc[mi][ni][e] = 0.f;

    for (int kk = 0; kk < K; kk += 32) {
        if (pairX) {
#pragma unroll
            for (int t = 0; t < 2; ++t) {
                int c = tid + t * 256;      // 512 chunks of 8 bf16
                int r = c >> 2, kc = (c & 3) * 8;
                int gr = row0 + r;
                const float* xp = pairX + (size_t)(gr >> 8) * K + kk + kc;
                const float* yp = pairY + (size_t)(gr & 255) * K + kk + kc;
                f32x4 x0 = *(const f32x4*)xp, x1 = *(const f32x4*)(xp + 4);
                f32x4 y0 = *(const f32x4*)yp, y1 = *(const f32x4*)(yp + 4);
                f32x4 sa = *(const f32x4*)(ps + kk + kc);
                f32x4 sb = *(const f32x4*)(ps + kk + kc + 4);
                f32x4 oa = *(const f32x4*)(po + kk + kc);
                f32x4 ob = *(const f32x4*)(po + kk + kc + 4);
                bf16x8 dv;
#pragma unroll
                for (int j = 0; j < 4; ++j) {
                    float d0 = x0[j] - y0[j];
                    float d1 = x1[j] - y1[j];
                    dv[j]     = (bf16)(d0 * d0 * sa[j] + oa[j]);
                    dv[j + 4] = (bf16)(d1 * d1 * sb[j] + ob[j]);
                }
                *(bf16x8*)&As[r * 32 + kc] = dv;
            }
        } else {
#pragma unroll
            for (int t = 0; t < 2; ++t) {
                int c = wave + t * 4;       // 16-row chunk 0..7
                async_load16(A + (size_t)(row0 + c * 16 + ar) * K + kk + akc,
                             &As[c * 512 + lane * 8]);
            }
        }
#pragma unroll
        for (int t = 0; t < 2; ++t) {
            int c = wave + t * 4;
            async_load16(Bp + (size_t)(col0 + c * 16 + ar) * K + kk + akc,
                         &Bs[c * 512 + lane * 8]);
        }
        __syncthreads();

        bf16x8 af[4], bfr[4];
#pragma unroll
        for (int mi = 0; mi < 4; ++mi)
            af[mi] = *(const bf16x8*)&As[(wr * 64 + mi * 16 + l16) * 32 + k0];
#pragma unroll
        for (int ni = 0; ni < 4; ++ni)
            bfr[ni] = *(const bf16x8*)&Bs[(wc * 64 + ni * 16 + l16) * 32 + k0];
#pragma unroll
        for (int mi = 0; mi < 4; ++mi)
#pragma unroll
            for (int ni = 0; ni < 4; ++ni)
                acc[mi][ni] = __builtin_amdgcn_mfma_f32_16x16x32_bf16(
                    af[mi], bfr[ni], acc[mi][ni], 0, 0, 0);
        __syncthreads();
    }

    // C/D layout (m89-verified): col = lane&15, row = (lane>>4)*4 + reg
    if (fuseW) {
#pragma unroll
        for (int mi = 0; mi < 4; ++mi)
#pragma unroll
            for (int i = 0; i < 4; ++i) {
                float rs = 0.f;
#pragma unroll
                for (int ni = 0; ni < 4; ++ni) {
                    int cc = col0 + wc * 64 + ni * 16 + l16;
                    float val = acc[mi][ni][i] * scale[cc] + offset[cc];
                    val = val > 0.f ? val : 0.1f * val;
                    rs += val * fuseW[cc];
                }
                rs += __shfl_xor(rs, 1, 64);
                rs += __shfl_xor(rs, 2, 64);
                rs += __shfl_xor(rs, 4, 64);
                rs += __shfl_xor(rs, 8, 64);
                if (l16 == 0) {
                    int r = row0 + wr * 64 + mi * 16 + q * 4 + i;
                    atomicAdd(facc + (size_t)blockIdx.z * faccStride + r, rs);
                }
            }
        return;
    }
#pragma unroll
    for (int mi = 0; mi < 4; ++mi)
#pragma unroll
        for (int ni = 0; ni < 4; ++ni)
#pragma unroll
            for (int i = 0; i < 4; ++i) {
                int r = row0 + wr * 64 + mi * 16 + q * 4 + i;
                int cc = col0 + wc * 64 + ni * 16 + l16;
                float val = acc[mi][ni][i];
                if (scale) val = val * scale[cc] + offset[cc];
                if (lrelu) val = val > 0.f ? val : 0.1f * val;
                Cp[(size_t)r * N + cc] = (bf16)val;
            }
}

extern "C" void kernel_launch(void* const* d_in, const int* in_sizes, int n_in,
                              void* d_out, int out_size, void* d_ws, size_t ws_size,
                              hipStream_t stream)
{
    const float* f_p   = (const float*)d_in[0];
    const float* f_g   = (const float*)d_in[1];
    const float* bn_g  = (const float*)d_in[2];
    const float* bn_b  = (const float*)d_in[3];
    const float* bn_m  = (const float*)d_in[4];
    const float* bn_v  = (const float*)d_in[5];
    const float* rf_W1 = (const float*)d_in[6];
    const float* rf_b1 = (const float*)d_in[7];
    const float* rf1_g = (const float*)d_in[8];
    const float* rf1_b = (const float*)d_in[9];
    const float* rf1_m = (const float*)d_in[10];
    const float* rf1_v = (const float*)d_in[11];
    const float* rf_W2 = (const float*)d_in[12];
    const float* rf_b2 = (const float*)d_in[13];
    const float* rf2_g = (const float*)d_in[14];
    const float* rf2_b = (const float*)d_in[15];
    const float* rf2_m = (const float*)d_in[16];
    const float* rf2_v = (const float*)d_in[17];
    const float* sfc_W = (const float*)d_in[18];
    const float* sfc_b = (const float*)d_in[19];
    const float* sbn_g = (const float*)d_in[20];
    const float* sbn_b = (const float*)d_in[21];
    const float* sbn_m = (const float*)d_in[22];
    const float* sbn_v = (const float*)d_in[23];
    const float* scl_W = (const float*)d_in[24];
    const float* scl_b = (const float*)d_in[25];
    const float* ffc_W = (const float*)d_in[26];
    const float* ffc_b = (const float*)d_in[27];
    const float* fbn_g = (const float*)d_in[28];
    const float* fbn_b = (const float*)d_in[29];
    const float* fbn_m = (const float*)d_in[30];
    const float* fbn_v = (const float*)d_in[31];
    const float* cls_W = (const float*)d_in[32];
    const float* cls_b = (const float*)d_in[33];

    const size_t MB = 1ull << 20;
    char* ws = (char*)d_ws;
    // --- static region: first 8 MiB ---
    float* SC      = (float*)(ws);               // 32 KiB
    float *s0 = SC,        *o0 = SC + 1024;
    float *s1 = SC + 2048, *o1 = SC + 3072;
    float *s2 = SC + 4096, *o2 = SC + 5120;
    float *s3 = SC + 6144, *o3 = SC + 6656;
    float *s4 = SC + 7168, *o4 = SC + 7680;
    float* w_acc   = (float*)(ws + 65536);       // 256 KiB
    float* out_acc = (float*)(ws + 327680);      // 128 KiB
    bf16* wT       = (bf16*)(ws + 458752);       // 128 KiB
    bf16* W1T      = (bf16*)(ws + 1 * MB);       // 2 MiB
    bf16* W2T      = (bf16*)(ws + 3 * MB);       // 2 MiB
    bf16* sfcT     = (bf16*)(ws + 5 * MB);       // 1 MiB
    bf16* ffcT     = (bf16*)(ws + 6 * MB);       // 1 MiB
    // --- chunked region @ 8 MiB ---
    int nc;
    if      (ws_size >= 170 * MB) nc = 1;
    else if (ws_size >= 90 * MB)  nc = 2;
    else if (ws_size >= 48 * MB)  nc = 4;
    else if (ws_size >= 28 * MB)  nc = 8;
    else                          nc = 16;
    const int pc = 128 / nc;
    const int R  = pc * 256;
    const size_t hbytes = (size_t)R * 1024 * 2;
    bf16* bufA = (bf16*)(ws + 8 * MB);
    bf16* bufB = (bf16*)(ws + 8 * MB + hbytes);
    bf16* bufC = (bf16*)(ws + 8 * MB + 2 * hbytes);

    // 1. BN folds
    prep_kernel<<<dim3(4), 256, 0, stream>>>(bn_g, bn_b, bn_m, bn_v, nullptr, s0, o0, 1024);
    prep_kernel<<<dim3(4), 256, 0, stream>>>(rf1_g, rf1_b, rf1_m, rf1_v, rf_b1, s1, o1, 1024);
    prep_kernel<<<dim3(4), 256, 0, stream>>>(rf2_g, rf2_b, rf2_m, rf2_v, rf_b2, s2, o2, 1024);
    prep_kernel<<<dim3(2), 256, 0, stream>>>(sbn_g, sbn_b, sbn_m, sbn_v, sfc_b, s3, o3, 512);
    prep_kernel<<<dim3(2), 256, 0, stream>>>(fbn_g, fbn_b, fbn_m, fbn_v, ffc_b, s4, o4, 512);

    // 2. weight transposes (f32 -> bf16)
    wtrans_kernel<<<dim3(4, 1024), 256, 0, stream>>>(rf_W1, W1T, 1024, 1024);
    wtrans_kernel<<<dim3(4, 1024), 256, 0, stream>>>(rf_W2, W2T, 1024, 1024);
    wtrans_kernel<<<dim3(4, 512), 256, 0, stream>>>(sfc_W, sfcT, 1024, 512);
    wtrans_kernel<<<dim3(4, 512), 256, 0, stream>>>(ffc_W, ffcT, 1024, 512);

    // 3. zero accumulators (w_acc + out_acc contiguous)
    hipMemsetAsync(ws + 65536, 0, 393216, stream);

    // 4. fused+symmetric affinity: w[g1][g2] = sum_h lrelu(sbn(dg@sfc_W))*scl_W
    gemm_kernel<<<dim3(4, 384, 1), 256, 0, stream>>>(
        nullptr, f_g, f_g, s0, o0, sfcT, nullptr, 1024, 512, 0, 0,
        s3, o3, 1, 1, scl_W, w_acc, 0);
    // 5. wT[g2][g1] = bf16(w[canon] + scl_b)
    wconv_kernel<<<dim3(256), 256, 0, stream>>>(w_acc, scl_b, wT);

    // 6. probe chunks
    for (int ci = 0; ci < nc; ++ci) {
        const float* fp_c = f_p + (size_t)ci * pc * 1024;
        // h = lrelu(rf1(d @ W1 + b1))      [R,1024] -> bufA
        gemm_kernel<<<dim3(8, R / 128, 1), 256, 0, stream>>>(
            nullptr, fp_c, f_g, s0, o0, W1T, bufA, 1024, 1024, 0, 0,
            s1, o1, 1, 0, nullptr, nullptr, 0);
        // t = lrelu(rf2(h @ W2 + b2))      [R,1024] -> bufB
        gemm_kernel<<<dim3(8, R / 128, 1), 256, 0, stream>>>(
            bufA, nullptr, nullptr, nullptr, nullptr, W2T, bufB, 1024, 1024, 0, 0,
            s2, o2, 1, 0, nullptr, nullptr, 0);
        // u = t @ ffc_W                    [R,512] -> bufC
        gemm_kernel<<<dim3(4, R / 128, 1), 256, 0, stream>>>(
            bufB, nullptr, nullptr, nullptr, nullptr, ffcT, bufC, 1024, 512, 0, 0,
            nullptr, nullptr, 0, 0, nullptr, nullptr, 0);
        // uT[p][h][g]                      -> bufA
        utrans_kernel<<<dim3(4, 8, pc), 256, 0, stream>>>(bufC, bufA);
        // fused feat+classifier: lrelu(fbn(wT @ uT + b)) . cls_W -> out_acc
        gemm_kernel<<<dim3(4, 2, pc), 256, 0, stream>>>(
            wT, nullptr, nullptr, nullptr, nullptr, bufA, nullptr, 256, 512,
            (long long)512 * 256, 0, s4, o4, 1, 0,
            cls_W, out_acc + (size_t)ci * pc * 256, 256);
    }
    // 7. d_out = out_acc + cls_b
    finout_kernel<<<dim3(128), 256, 0, stream>>>(out_acc, cls_b, (float*)d_out);
}